// Round 6
// baseline (255.997 us; speedup 1.0000x reference)
//
#include <hip/hip_runtime.h>
#include <hip/hip_bf16.h>

typedef unsigned short u16;
typedef unsigned int u32;
typedef __attribute__((ext_vector_type(8))) short short8;
typedef __attribute__((ext_vector_type(4))) float f32x4;

#define B_ 4
#define T_ 1024
#define E_ 1024
#define NH 16
#define HD 1024
#define JTOT 2048
#define SCALE 0.125f
#define LOG2E 1.44269504f

// ---------- helpers ----------
__device__ __forceinline__ u16 f2b(float f) {
  u32 x = __float_as_uint(f);
  u32 r = (x + 0x7fffu + ((x >> 16) & 1u)) >> 16;  // RNE
  return (u16)r;
}
__device__ __forceinline__ u16 f2b_fast(float f) {  // round-half-up (2 ops)
  return (u16)((__float_as_uint(f) + 0x8000u) >> 16);
}
__device__ __forceinline__ float b2f(u16 b) {
  return __uint_as_float((u32)b << 16);
}
__device__ __forceinline__ float fexp2(float x) {
  float r;
  asm("v_exp_f32 %0, %1" : "=v"(r) : "v"(x));
  return r;
}

__device__ __forceinline__ void gload_lds16(const void* g, void* l) {
  __builtin_amdgcn_global_load_lds((const __attribute__((address_space(1))) u32*)g,
                                   (__attribute__((address_space(3))) u32*)l, 16, 0, 0);
}

__device__ __forceinline__ short8 pack8(float4 f0, float4 f1) {
  short8 o;
  o[0] = (short)f2b(f0.x); o[1] = (short)f2b(f0.y);
  o[2] = (short)f2b(f0.z); o[3] = (short)f2b(f0.w);
  o[4] = (short)f2b(f1.x); o[5] = (short)f2b(f1.y);
  o[6] = (short)f2b(f1.z); o[7] = (short)f2b(f1.w);
  return o;
}

// ---------- conversion kernels ----------
__global__ __launch_bounds__(256) void cvt_bf16(const float* __restrict__ in,
                                                u16* __restrict__ out, int n8) {
  int i = blockIdx.x * 256 + threadIdx.x;
  if (i >= n8) return;
  const float4* p = (const float4*)in + (size_t)i * 2;
  ((short8*)out)[i] = pack8(p[0], p[1]);
}

// fused 4x: W [1024][1024] f32 -> WT bf16 transposed
__global__ __launch_bounds__(256) void cvt_w4T(const float* __restrict__ Wq, const float* __restrict__ Wk,
                                               const float* __restrict__ Wv, const float* __restrict__ Wo,
                                               u16* __restrict__ wqkvT, u16* __restrict__ woT) {
  __shared__ float tile[64][65];
  const float* W;
  u16* WT;
  int z = blockIdx.z;
  if (z == 0) { W = Wq; WT = wqkvT; }
  else if (z == 1) { W = Wk; WT = wqkvT + (size_t)1024 * 1024; }
  else if (z == 2) { W = Wv; WT = wqkvT + (size_t)2048 * 1024; }
  else { W = Wo; WT = woT; }
  int t = threadIdx.x;
  int r0 = blockIdx.y * 64, c0 = blockIdx.x * 64;
#pragma unroll
  for (int i = 0; i < 16; ++i) {
    int r = i * 4 + (t >> 6), c = t & 63;
    tile[r][c] = W[(size_t)(r0 + r) * 1024 + c0 + c];
  }
  __syncthreads();
#pragma unroll
  for (int i = 0; i < 16; ++i) {
    int r = i * 4 + (t >> 6), c = t & 63;
    WT[(size_t)(c0 + r) * 1024 + r0 + c] = f2b(tile[c][r]);
  }
}

// xl k-half -> kt tiles [B][H][jc 0..15][64 j][64 d ^ octet-swz] bf16
__global__ __launch_bounds__(256) void cvt_xl_k(const float* __restrict__ xl, u16* __restrict__ kt) {
  int i = blockIdx.x * 256 + threadIdx.x;  // [0, 524288)
  int hd8 = i & 127, j = (i >> 7) & 1023, b = i >> 17;
  const float4* p = (const float4*)(xl + ((((size_t)b * 1024 + j) * 2 + 0) * 1024 + (size_t)hd8 * 8));
  short8 o = pack8(p[0], p[1]);
  int h = hd8 >> 3, d0 = (hd8 & 7) * 8;
  int jc = j >> 6, jl = j & 63;
  u16* dst = kt + (((size_t)(b * 16 + h) * 32 + jc) * 4096) + jl * 64 + (d0 ^ ((jl & 7) << 3));
  *(short8*)dst = o;
}

// xl v-half -> vt tiles [B][H][jc 0..15][64 d][64 j ^ octet-swz] bf16 (transposed)
__global__ __launch_bounds__(256) void cvt_xl_vT(const float* __restrict__ xl, u16* __restrict__ vt) {
  __shared__ u16 Vl[64 * 72];
  int bx = blockIdx.x;
  int jc = bx & 15, h = (bx >> 4) & 15, b = bx >> 8;
  int t = threadIdx.x;
  int j0 = jc * 64;
#pragma unroll
  for (int it = 0; it < 2; ++it) {
    int p = t + 256 * it;
    int j = p >> 3, d8 = p & 7;
    const float4* src = (const float4*)(xl + ((((size_t)b * 1024 + j0 + j) * 2 + 1) * 1024 + h * 64 + (size_t)d8 * 8));
    *(short8*)&Vl[j * 72 + d8 * 8] = pack8(src[0], src[1]);
  }
  __syncthreads();
#pragma unroll
  for (int it = 0; it < 2; ++it) {
    int p = t + 256 * it;
    int d = p >> 3, j8 = p & 7;
    short8 o;
#pragma unroll
    for (int e = 0; e < 8; ++e) o[e] = (short)Vl[(j8 * 8 + e) * 72 + d];
    u16* dst = vt + (((size_t)(b * 16 + h) * 32 + jc) * 4096) + d * 64 + ((j8 * 8) ^ ((d & 7) << 3));
    *(short8*)dst = o;
  }
}

// vb_new [b][tt][hd] bf16 -> vt tiles jc 16..31 (transposed + octet-swizzled)
__global__ __launch_bounds__(256) void trans_vnew(const u16* __restrict__ vb, u16* __restrict__ vt) {
  __shared__ u16 Vl[64 * 72];
  int bx = blockIdx.x;
  int jcl = bx & 15, h = (bx >> 4) & 15, b = bx >> 8;
  int jc = 16 + jcl;
  int t = threadIdx.x;
  int t0 = jcl * 64;
#pragma unroll
  for (int it = 0; it < 2; ++it) {
    int p = t + 256 * it;
    int j = p >> 3, d8 = p & 7;
    *(short8*)&Vl[j * 72 + d8 * 8] =
        *(const short8*)&vb[((size_t)b * 1024 + t0 + j) * 1024 + h * 64 + d8 * 8];
  }
  __syncthreads();
#pragma unroll
  for (int it = 0; it < 2; ++it) {
    int p = t + 256 * it;
    int d = p >> 3, j8 = p & 7;
    short8 o;
#pragma unroll
    for (int e = 0; e < 8; ++e) o[e] = (short)Vl[(j8 * 8 + e) * 72 + d];
    u16* dst = vt + (((size_t)(b * 16 + h) * 32 + jc) * 4096) + d * 64 + ((j8 * 8) ^ ((d & 7) << 3));
    *(short8*)dst = o;
  }
}

// ---------- QKV GEMM: 128x128 tiles, slim epilogue ----------
__global__ __launch_bounds__(256) void gemm_qkv(
    const u16* __restrict__ A, const u16* __restrict__ BT,
    const float* __restrict__ b0, const float* __restrict__ b1, const float* __restrict__ b2,
    u16* __restrict__ qb, u16* __restrict__ kbp, u16* __restrict__ kt, u16* __restrict__ vb) {
  __shared__ __align__(16) u16 As[128 * 32];
  __shared__ __align__(16) u16 Bs[128 * 32];
  const int t = threadIdx.x;
  const int lane = t & 63, wv = t >> 6;
  const int wr = wv >> 1, wc = wv & 1;
  const int m0 = (blockIdx.x / 24) * 128;
  const int n0 = (blockIdx.x % 24) * 128;
  const int lr = lane & 15, lg = lane >> 4;

  f32x4 acc[4][4] = {};

  for (int kc = 0; kc < 1024; kc += 32) {
    __syncthreads();
#pragma unroll
    for (int i = 0; i < 2; ++i) {
      int p = t + 256 * i;
      gload_lds16(A + (size_t)(m0 + (p >> 2)) * 1024 + kc + (p & 3) * 8, &As[p * 8]);
    }
#pragma unroll
    for (int i = 0; i < 2; ++i) {
      int p = t + 256 * i;
      gload_lds16(BT + (size_t)(n0 + (p >> 2)) * 1024 + kc + (p & 3) * 8, &Bs[p * 8]);
    }
    __syncthreads();

    short8 af[4], bf[4];
#pragma unroll
    for (int mf = 0; mf < 4; ++mf)
      af[mf] = *(const short8*)&As[(wr * 64 + mf * 16 + lr) * 32 + lg * 8];
#pragma unroll
    for (int nf = 0; nf < 4; ++nf)
      bf[nf] = *(const short8*)&Bs[(wc * 64 + nf * 16 + lr) * 32 + lg * 8];
#pragma unroll
    for (int mf = 0; mf < 4; ++mf)
#pragma unroll
      for (int nf = 0; nf < 4; ++nf)
        acc[mf][nf] = __builtin_amdgcn_mfma_f32_16x16x32_bf16(af[mf], bf[nf], acc[mf][nf], 0, 0, 0);
  }

#pragma unroll
  for (int mf = 0; mf < 4; ++mf) {
#pragma unroll
    for (int nf = 0; nf < 4; ++nf) {
#pragma unroll
      for (int r = 0; r < 4; ++r) {
        int row = m0 + wr * 64 + mf * 16 + lg * 4 + r;
        int col = n0 + wc * 64 + nf * 16 + lr;
        float v = acc[mf][nf][r];
        int b = row >> 10, tt = row & 1023;
        if (col < 1024) {
          v += b0[col];
          qb[(size_t)row * HD + col] = f2b(v * (SCALE * SCALE * LOG2E));
        } else if (col < 2048) {
          int hd = col - 1024;
          u16 kv16 = f2b(v + b1[hd]);
          kbp[(size_t)(b * 1024 + tt) * 1024 + hd] = kv16;
          int h = hd >> 6, d = hd & 63, jl = tt & 63, jc = 16 + (tt >> 6);
          kt[(((size_t)(b * 16 + h) * 32 + jc) * 4096) + jl * 64 + (d ^ ((jl & 7) << 3))] = kv16;
        } else {
          int hd = col - 2048;
          vb[(size_t)(b * 1024 + tt) * 1024 + hd] = f2b(v + b2[hd]);
        }
      }
    }
  }
}

// kvout [b][t][2][1024] f32 from plain bf16 k/v (coalesced)
__global__ __launch_bounds__(256) void kv_expand(const u16* __restrict__ kbp, const u16* __restrict__ vbp,
                                                 float* __restrict__ kvout) {
  int i = blockIdx.x * 256 + threadIdx.x;  // [0, 524288)
  int hd8 = i & 127, tt = (i >> 7) & 1023, b = i >> 17;
  size_t src = ((size_t)(b * 1024 + tt)) * 1024 + (size_t)hd8 * 8;
  short8 k8 = *(const short8*)&kbp[src];
  short8 v8 = *(const short8*)&vbp[src];
  float4 k0, k1, v0, v1;
#pragma unroll
  for (int e = 0; e < 4; ++e) {
    ((float*)&k0)[e] = b2f((u16)k8[e]); ((float*)&k1)[e] = b2f((u16)k8[e + 4]);
    ((float*)&v0)[e] = b2f((u16)v8[e]); ((float*)&v1)[e] = b2f((u16)v8[e + 4]);
  }
  float* kdst = kvout + (((size_t)(b * 1024 + tt) * 2 + 0) * 1024) + hd8 * 8;
  float* vdst = kvout + (((size_t)(b * 1024 + tt) * 2 + 1) * 1024) + hd8 * 8;
  ((float4*)kdst)[0] = k0; ((float4*)kdst)[1] = k1;
  ((float4*)vdst)[0] = v0; ((float4*)vdst)[1] = v1;
}

// ---------- out-proj GEMM: 64x128 tiles, 512 blocks ----------
__global__ __launch_bounds__(256) void gemm_out(
    const u16* __restrict__ A, const u16* __restrict__ BT,
    const float* __restrict__ bias, float* __restrict__ outf) {
  __shared__ __align__(16) u16 As[64 * 32];
  __shared__ __align__(16) u16 Bs[128 * 32];
  const int t = threadIdx.x;
  const int lane = t & 63, wv = t >> 6;
  const int wr = wv >> 1, wc = wv & 1;
  const int m0 = (blockIdx.x >> 3) * 64;
  const int n0 = (blockIdx.x & 7) * 128;
  const int lr = lane & 15, lg = lane >> 4;

  f32x4 acc[2][4] = {};

  for (int kc = 0; kc < 1024; kc += 32) {
    __syncthreads();
    gload_lds16(A + (size_t)(m0 + (t >> 2)) * 1024 + kc + (t & 3) * 8, &As[t * 8]);
#pragma unroll
    for (int i = 0; i < 2; ++i) {
      int p = t + 256 * i;
      gload_lds16(BT + (size_t)(n0 + (p >> 2)) * 1024 + kc + (p & 3) * 8, &Bs[p * 8]);
    }
    __syncthreads();

    short8 af[2], bf[4];
#pragma unroll
    for (int mf = 0; mf < 2; ++mf)
      af[mf] = *(const short8*)&As[(wr * 32 + mf * 16 + lr) * 32 + lg * 8];
#pragma unroll
    for (int nf = 0; nf < 4; ++nf)
      bf[nf] = *(const short8*)&Bs[(wc * 64 + nf * 16 + lr) * 32 + lg * 8];
#pragma unroll
    for (int mf = 0; mf < 2; ++mf)
#pragma unroll
      for (int nf = 0; nf < 4; ++nf)
        acc[mf][nf] = __builtin_amdgcn_mfma_f32_16x16x32_bf16(af[mf], bf[nf], acc[mf][nf], 0, 0, 0);
  }

#pragma unroll
  for (int mf = 0; mf < 2; ++mf)
#pragma unroll
    for (int nf = 0; nf < 4; ++nf)
#pragma unroll
      for (int r = 0; r < 4; ++r) {
        int row = m0 + wr * 32 + mf * 16 + lg * 4 + r;
        int col = n0 + wc * 64 + nf * 16 + lr;
        outf[(size_t)row * E_ + col] = acc[mf][nf][r] + bias[col];
      }
}

// ---------- flash attention: QBLK=128, 4 waves x 32 rows, conflict-free K/V ----------
__global__ __launch_bounds__(256) void attn_kernel(
    const u16* __restrict__ qb, const u16* __restrict__ kt, const u16* __restrict__ vt,
    const float* __restrict__ rel, u16* __restrict__ aout) {
  __shared__ __align__(16) u16 Ks[2][4096];
  __shared__ __align__(16) u16 Vs[2][4096];
  __shared__ __align__(16) u16 Pl[8192];
  const int bx = blockIdx.x;
  const int b = bx & 3, h = (bx >> 2) & 15;
  const int q_ = bx >> 6;
  const int qt = q_ < 4 ? q_ : 11 - q_;  // pair (q,7-q) on each CU: uniform 50 chunks
  const int i0 = qt * 128;
  const int t = threadIdx.x, lane = t & 63, w = t >> 6;
  const int lr = lane & 15, lg = lane >> 4;
  const int swz = (lr & 7) << 3;           // octet swizzle for K/V reads
  const int psw = ((lr >> 2) & 3) << 4;    // P-tile swizzle (unchanged scheme)
  const float RC = SCALE * LOG2E;

  const u16* ktb = kt + (size_t)(b * 16 + h) * 32 * 4096;
  const u16* vtb = vt + (size_t)(b * 16 + h) * 32 * 4096;
  const float* relbase = rel + (size_t)h * T_ * JTOT;

  short8 qf[2][2];
#pragma unroll
  for (int mf = 0; mf < 2; ++mf)
#pragma unroll
    for (int kc = 0; kc < 2; ++kc)
      qf[mf][kc] = *(const short8*)&qb[(size_t)(b * T_ + i0 + w * 32 + mf * 16 + lr) * HD + h * 64 + kc * 32 + lg * 8];

  short8 vf5;
#pragma unroll
  for (int e = 0; e < 8; ++e) vf5[e] = (lr == 0) ? (short)0x3f80 : (short)0;

  const int nch = qt * 2 + 18;

  auto stage = [&](int buf, int jc2) {  // 4 VMEM instrs/thread
    const u16* ksrc = ktb + (size_t)jc2 * 4096;
    const u16* vsrc = vtb + (size_t)jc2 * 4096;
    gload_lds16(ksrc + t * 8, &Ks[buf][t * 8]);
    gload_lds16(ksrc + (t + 256) * 8, &Ks[buf][(t + 256) * 8]);
    gload_lds16(vsrc + t * 8, &Vs[buf][t * 8]);
    gload_lds16(vsrc + (t + 256) * 8, &Vs[buf][(t + 256) * 8]);
  };

  float rl[2][4][4];
  auto loadrel = [&](int j0) {  // 32 VMEM dword loads/thread
#pragma unroll
    for (int mf = 0; mf < 2; ++mf) {
      const float* rb = relbase + (size_t)(i0 + w * 32 + mf * 16 + lg * 4) * JTOT + j0;
#pragma unroll
      for (int nf = 0; nf < 4; ++nf)
#pragma unroll
        for (int r = 0; r < 4; ++r)
          rl[mf][nf][r] = rb[(size_t)r * JTOT + nf * 16 + lr];
    }
  };

  stage(0, 0);
  __builtin_amdgcn_sched_barrier(0);  // stage(0) VMEM issued before rel(0): vmcnt count valid
  loadrel(0);

  f32x4 o[2][4] = {};
  f32x4 o5[2] = {};  // running row-sum via ones-column MFMA
  float mrow[2][4];
#pragma unroll
  for (int mf = 0; mf < 2; ++mf)
#pragma unroll
    for (int r = 0; r < 4; ++r) mrow[mf][r] = -__builtin_inff();

  int cur = 0;
  for (int jc = 0; jc < nch; ++jc) {
    // own stage(jc) = oldest 4 of ≤36 outstanding; 32 rel loads stay in flight
    asm volatile("s_waitcnt vmcnt(32)" ::: "memory");
    __builtin_amdgcn_sched_barrier(0);
    asm volatile("s_barrier" ::: "memory");
    if (jc + 1 < nch) stage(cur ^ 1, jc + 1);
    __builtin_amdgcn_sched_barrier(0);

    // S = Q K^T (log2 domain): K frag loaded once, reused across both mf
    f32x4 s4[2][4] = {};
    __builtin_amdgcn_s_setprio(1);
#pragma unroll
    for (int nf = 0; nf < 4; ++nf)
#pragma unroll
      for (int kc = 0; kc < 2; ++kc) {
        short8 kf = *(const short8*)&Ks[cur][(nf * 16 + lr) * 64 + ((kc * 32 + lg * 8) ^ swz)];
#pragma unroll
        for (int mf = 0; mf < 2; ++mf)
          s4[mf][nf] = __builtin_amdgcn_mfma_f32_16x16x32_bf16(qf[mf][kc], kf, s4[mf][nf], 0, 0, 0);
      }
    __builtin_amdgcn_s_setprio(0);

    // logits + in-lane max
    float p[2][4][4], lmax[2][4];
    const bool domask = (jc >= nch - 2);
#pragma unroll
    for (int mf = 0; mf < 2; ++mf) {
      const int ibm = i0 + w * 32 + mf * 16 + lg * 4 + 1024 - jc * 64;  // i+1024-j0 base
#pragma unroll
      for (int nf = 0; nf < 4; ++nf)
#pragma unroll
        for (int r = 0; r < 4; ++r) {
          float v = fmaf(rl[mf][nf][r], RC, s4[mf][nf][r]);
          if (domask && (nf * 16 + lr) > (ibm + r)) v = -__builtin_inff();
          p[mf][nf][r] = v;
        }
#pragma unroll
      for (int r = 0; r < 4; ++r)
        lmax[mf][r] = fmaxf(fmaxf(p[mf][0][r], p[mf][1][r]), fmaxf(p[mf][2][r], p[mf][3][r]));
    }
    if (jc + 1 < nch) loadrel((jc + 1) * 64);  // issue early, consumed next iter

    // defer-max: cross-lane tree only when rescale needed
    float need = -__builtin_inff();
#pragma unroll
    for (int mf = 0; mf < 2; ++mf)
#pragma unroll
      for (int r = 0; r < 4; ++r) need = fmaxf(need, lmax[mf][r] - mrow[mf][r]);
    const bool dores = !__all(need <= 11.0f);
    if (dores) {
#pragma unroll
      for (int mf = 0; mf < 2; ++mf) {
        float chmax[4], sc[4];
#pragma unroll
        for (int r = 0; r < 4; ++r) chmax[r] = lmax[mf][r];
#pragma unroll
        for (int msk = 1; msk <= 8; msk <<= 1)
#pragma unroll
          for (int r = 0; r < 4; ++r)
            chmax[r] = fmaxf(chmax[r], __shfl_xor(chmax[r], msk, 64));
#pragma unroll
        for (int r = 0; r < 4; ++r) {
          float nm = fmaxf(mrow[mf][r], chmax[r]);
          sc[r] = fexp2(mrow[mf][r] - nm);
          mrow[mf][r] = nm;
        }
#pragma unroll
        for (int nf = 0; nf < 4; ++nf)
#pragma unroll
          for (int r = 0; r < 4; ++r) o[mf][nf][r] *= sc[r];
#pragma unroll
        for (int r = 0; r < 4; ++r) o5[mf][r] *= sc[r];
      }
    }

    // P = exp2(p - m) -> wave-private swizzled LDS (rows w*32..w*32+31)
#pragma unroll
    for (int mf = 0; mf < 2; ++mf)
#pragma unroll
      for (int nf = 0; nf < 4; ++nf)
#pragma unroll
        for (int r = 0; r < 4; ++r) {
          float pe = fexp2(p[mf][nf][r] - mrow[mf][r]);
          Pl[(w * 32 + mf * 16 + lg * 4 + r) * 64 + (((nf ^ lg) << 4) + lr)] = f2b_fast(pe);
        }

    // O += P @ V; V frag loaded once, reused across both mf
    __builtin_amdgcn_s_setprio(1);
#pragma unroll
    for (int kc = 0; kc < 2; ++kc) {
      short8 vf[4];
#pragma unroll
      for (int nf = 0; nf < 4; ++nf)
        vf[nf] = *(const short8*)&Vs[cur][(nf * 16 + lr) * 64 + ((kc * 32 + lg * 8) ^ swz)];
#pragma unroll
      for (int mf = 0; mf < 2; ++mf) {
        short8 pa = *(const short8*)&Pl[(w * 32 + mf * 16 + lr) * 64 + ((kc * 32 + lg * 8) ^ psw)];
#pragma unroll
        for (int nf = 0; nf < 4; ++nf)
          o[mf][nf] = __builtin_amdgcn_mfma_f32_16x16x32_bf16(pa, vf[nf], o[mf][nf], 0, 0, 0);
        o5[mf] = __builtin_amdgcn_mfma_f32_16x16x32_bf16(pa, vf5, o5[mf], 0, 0, 0);
      }
    }
    __builtin_amdgcn_s_setprio(0);
    asm volatile("" ::: "memory");
    cur ^= 1;
  }

  // epilogue: broadcast row-sum (lanes lr==0), normalize, store
#pragma unroll
  for (int mf = 0; mf < 2; ++mf) {
    float inv[4];
#pragma unroll
    for (int r = 0; r < 4; ++r)
      inv[r] = 1.0f / __shfl(o5[mf][r], lane & 48, 64);
#pragma unroll
    for (int nf = 0; nf < 4; ++nf)
#pragma unroll
      for (int r = 0; r < 4; ++r) {
        int i = i0 + w * 32 + mf * 16 + lg * 4 + r, d = nf * 16 + lr;
        aout[(size_t)(b * T_ + i) * HD + h * 64 + d] = f2b_fast(o[mf][nf][r] * inv[r]);
      }
  }
}

// ---------- launch ----------
extern "C" void kernel_launch(void* const* d_in, const int* in_sizes, int n_in,
                              void* d_out, int out_size, void* d_ws, size_t ws_size,
                              hipStream_t stream) {
  const float* x  = (const float*)d_in[0];
  const float* xl = (const float*)d_in[1];
  const float* rel = (const float*)d_in[2];
  const float* Wq = (const float*)d_in[3];
  const float* bq = (const float*)d_in[4];
  const float* Wk = (const float*)d_in[5];
  const float* bk = (const float*)d_in[6];
  const float* Wv = (const float*)d_in[7];
  const float* bv = (const float*)d_in[8];
  const float* Wo = (const float*)d_in[9];
  const float* bo = (const float*)d_in[10];

  float* out = (float*)d_out;
  float* kvout = out + (size_t)B_ * T_ * E_;

  char* ws = (char*)d_ws;
  u16* xb    = (u16*)ws; ws += (size_t)4096 * 1024 * 2;
  u16* wqkvT = (u16*)ws; ws += (size_t)3072 * 1024 * 2;
  u16* woT   = (u16*)ws; ws += (size_t)1024 * 1024 * 2;
  u16* qbuf  = (u16*)ws; ws += (size_t)4096 * 1024 * 2;
  u16* kt    = (u16*)ws; ws += (size_t)B_ * NH * 32 * 4096 * 2;
  u16* vt    = (u16*)ws; ws += (size_t)B_ * NH * 32 * 4096 * 2;
  u16* vbn   = (u16*)ws; ws += (size_t)4096 * 1024 * 2;
  u16* kbp   = (u16*)ws; ws += (size_t)4096 * 1024 * 2;
  u16* aout  = (u16*)ws; ws += (size_t)4096 * 1024 * 2;

  cvt_bf16<<<2048, 256, 0, stream>>>(x, xb, 524288);
  cvt_w4T<<<dim3(16, 16, 4), 256, 0, stream>>>(Wq, Wk, Wv, Wo, wqkvT, woT);
  cvt_xl_k<<<2048, 256, 0, stream>>>(xl, kt);
  cvt_xl_vT<<<1024, 256, 0, stream>>>(xl, vt);

  gemm_qkv<<<32 * 24, 256, 0, stream>>>(xb, wqkvT, bq, bk, bv, qbuf, kbp, kt, vbn);
  kv_expand<<<2048, 256, 0, stream>>>(kbp, vbn, kvout);
  trans_vnew<<<1024, 256, 0, stream>>>(vbn, vt);
  attn_kernel<<<512, 256, 0, stream>>>(qbuf, kt, vt, rel, aout);
  gemm_out<<<512, 256, 0, stream>>>(aout, woT, bo, out);
}

// Round 7
// 226.381 us; speedup vs baseline: 1.1308x; 1.1308x over previous
//
#include <hip/hip_runtime.h>
#include <hip/hip_bf16.h>

typedef unsigned short u16;
typedef unsigned int u32;
typedef __attribute__((ext_vector_type(8))) short short8;
typedef __attribute__((ext_vector_type(4))) float f32x4;

#define B_ 4
#define T_ 1024
#define E_ 1024
#define NH 16
#define HD 1024
#define JTOT 2048
#define SCALE 0.125f
#define LOG2E 1.44269504f

// ---------- helpers ----------
__device__ __forceinline__ u16 f2b(float f) {
  u32 x = __float_as_uint(f);
  u32 r = (x + 0x7fffu + ((x >> 16) & 1u)) >> 16;  // RNE
  return (u16)r;
}
__device__ __forceinline__ u16 f2b_fast(float f) {  // round-half-up (2 ops)
  return (u16)((__float_as_uint(f) + 0x8000u) >> 16);
}
__device__ __forceinline__ float b2f(u16 b) {
  return __uint_as_float((u32)b << 16);
}
__device__ __forceinline__ float fexp2(float x) {
  float r;
  asm("v_exp_f32 %0, %1" : "=v"(r) : "v"(x));
  return r;
}

__device__ __forceinline__ void gload_lds16(const void* g, void* l) {
  __builtin_amdgcn_global_load_lds((const __attribute__((address_space(1))) u32*)g,
                                   (__attribute__((address_space(3))) u32*)l, 16, 0, 0);
}

__device__ __forceinline__ short8 pack8(float4 f0, float4 f1) {
  short8 o;
  o[0] = (short)f2b(f0.x); o[1] = (short)f2b(f0.y);
  o[2] = (short)f2b(f0.z); o[3] = (short)f2b(f0.w);
  o[4] = (short)f2b(f1.x); o[5] = (short)f2b(f1.y);
  o[6] = (short)f2b(f1.z); o[7] = (short)f2b(f1.w);
  return o;
}

// ---------- conversion kernels ----------
__global__ __launch_bounds__(256) void cvt_bf16(const float* __restrict__ in,
                                                u16* __restrict__ out, int n8) {
  int i = blockIdx.x * 256 + threadIdx.x;
  if (i >= n8) return;
  const float4* p = (const float4*)in + (size_t)i * 2;
  ((short8*)out)[i] = pack8(p[0], p[1]);
}

// fused 4x: W [1024][1024] f32 -> WT bf16 transposed
__global__ __launch_bounds__(256) void cvt_w4T(const float* __restrict__ Wq, const float* __restrict__ Wk,
                                               const float* __restrict__ Wv, const float* __restrict__ Wo,
                                               u16* __restrict__ wqkvT, u16* __restrict__ woT) {
  __shared__ float tile[64][65];
  const float* W;
  u16* WT;
  int z = blockIdx.z;
  if (z == 0) { W = Wq; WT = wqkvT; }
  else if (z == 1) { W = Wk; WT = wqkvT + (size_t)1024 * 1024; }
  else if (z == 2) { W = Wv; WT = wqkvT + (size_t)2048 * 1024; }
  else { W = Wo; WT = woT; }
  int t = threadIdx.x;
  int r0 = blockIdx.y * 64, c0 = blockIdx.x * 64;
#pragma unroll
  for (int i = 0; i < 16; ++i) {
    int r = i * 4 + (t >> 6), c = t & 63;
    tile[r][c] = W[(size_t)(r0 + r) * 1024 + c0 + c];
  }
  __syncthreads();
#pragma unroll
  for (int i = 0; i < 16; ++i) {
    int r = i * 4 + (t >> 6), c = t & 63;
    WT[(size_t)(c0 + r) * 1024 + r0 + c] = f2b(tile[c][r]);
  }
}

// xl k-half -> kt tiles [B][H][jc 0..15][64 j][64 d ^ octet-swz] bf16
__global__ __launch_bounds__(256) void cvt_xl_k(const float* __restrict__ xl, u16* __restrict__ kt) {
  int i = blockIdx.x * 256 + threadIdx.x;  // [0, 524288)
  int hd8 = i & 127, j = (i >> 7) & 1023, b = i >> 17;
  const float4* p = (const float4*)(xl + ((((size_t)b * 1024 + j) * 2 + 0) * 1024 + (size_t)hd8 * 8));
  short8 o = pack8(p[0], p[1]);
  int h = hd8 >> 3, d0 = (hd8 & 7) * 8;
  int jc = j >> 6, jl = j & 63;
  u16* dst = kt + (((size_t)(b * 16 + h) * 32 + jc) * 4096) + jl * 64 + (d0 ^ ((jl & 7) << 3));
  *(short8*)dst = o;
}

// xl v-half -> vt tiles [B][H][jc 0..15][64 d][64 j ^ octet-swz] bf16 (transposed)
__global__ __launch_bounds__(256) void cvt_xl_vT(const float* __restrict__ xl, u16* __restrict__ vt) {
  __shared__ u16 Vl[64 * 72];
  int bx = blockIdx.x;
  int jc = bx & 15, h = (bx >> 4) & 15, b = bx >> 8;
  int t = threadIdx.x;
  int j0 = jc * 64;
#pragma unroll
  for (int it = 0; it < 2; ++it) {
    int p = t + 256 * it;
    int j = p >> 3, d8 = p & 7;
    const float4* src = (const float4*)(xl + ((((size_t)b * 1024 + j0 + j) * 2 + 1) * 1024 + h * 64 + (size_t)d8 * 8));
    *(short8*)&Vl[j * 72 + d8 * 8] = pack8(src[0], src[1]);
  }
  __syncthreads();
#pragma unroll
  for (int it = 0; it < 2; ++it) {
    int p = t + 256 * it;
    int d = p >> 3, j8 = p & 7;
    short8 o;
#pragma unroll
    for (int e = 0; e < 8; ++e) o[e] = (short)Vl[(j8 * 8 + e) * 72 + d];
    u16* dst = vt + (((size_t)(b * 16 + h) * 32 + jc) * 4096) + d * 64 + ((j8 * 8) ^ ((d & 7) << 3));
    *(short8*)dst = o;
  }
}

// vb_new [b][tt][hd] bf16 -> vt tiles jc 16..31 (transposed + octet-swizzled)
__global__ __launch_bounds__(256) void trans_vnew(const u16* __restrict__ vb, u16* __restrict__ vt) {
  __shared__ u16 Vl[64 * 72];
  int bx = blockIdx.x;
  int jcl = bx & 15, h = (bx >> 4) & 15, b = bx >> 8;
  int jc = 16 + jcl;
  int t = threadIdx.x;
  int t0 = jcl * 64;
#pragma unroll
  for (int it = 0; it < 2; ++it) {
    int p = t + 256 * it;
    int j = p >> 3, d8 = p & 7;
    *(short8*)&Vl[j * 72 + d8 * 8] =
        *(const short8*)&vb[((size_t)b * 1024 + t0 + j) * 1024 + h * 64 + d8 * 8];
  }
  __syncthreads();
#pragma unroll
  for (int it = 0; it < 2; ++it) {
    int p = t + 256 * it;
    int d = p >> 3, j8 = p & 7;
    short8 o;
#pragma unroll
    for (int e = 0; e < 8; ++e) o[e] = (short)Vl[(j8 * 8 + e) * 72 + d];
    u16* dst = vt + (((size_t)(b * 16 + h) * 32 + jc) * 4096) + d * 64 + ((j8 * 8) ^ ((d & 7) << 3));
    *(short8*)dst = o;
  }
}

// ---------- QKV GEMM: 128x128 tiles, slim epilogue ----------
__global__ __launch_bounds__(256) void gemm_qkv(
    const u16* __restrict__ A, const u16* __restrict__ BT,
    const float* __restrict__ b0, const float* __restrict__ b1, const float* __restrict__ b2,
    u16* __restrict__ qb, u16* __restrict__ kbp, u16* __restrict__ kt, u16* __restrict__ vb) {
  __shared__ __align__(16) u16 As[128 * 32];
  __shared__ __align__(16) u16 Bs[128 * 32];
  const int t = threadIdx.x;
  const int lane = t & 63, wv = t >> 6;
  const int wr = wv >> 1, wc = wv & 1;
  const int m0 = (blockIdx.x / 24) * 128;
  const int n0 = (blockIdx.x % 24) * 128;
  const int lr = lane & 15, lg = lane >> 4;

  f32x4 acc[4][4] = {};

  for (int kc = 0; kc < 1024; kc += 32) {
    __syncthreads();
#pragma unroll
    for (int i = 0; i < 2; ++i) {
      int p = t + 256 * i;
      gload_lds16(A + (size_t)(m0 + (p >> 2)) * 1024 + kc + (p & 3) * 8, &As[p * 8]);
    }
#pragma unroll
    for (int i = 0; i < 2; ++i) {
      int p = t + 256 * i;
      gload_lds16(BT + (size_t)(n0 + (p >> 2)) * 1024 + kc + (p & 3) * 8, &Bs[p * 8]);
    }
    __syncthreads();

    short8 af[4], bf[4];
#pragma unroll
    for (int mf = 0; mf < 4; ++mf)
      af[mf] = *(const short8*)&As[(wr * 64 + mf * 16 + lr) * 32 + lg * 8];
#pragma unroll
    for (int nf = 0; nf < 4; ++nf)
      bf[nf] = *(const short8*)&Bs[(wc * 64 + nf * 16 + lr) * 32 + lg * 8];
#pragma unroll
    for (int mf = 0; mf < 4; ++mf)
#pragma unroll
      for (int nf = 0; nf < 4; ++nf)
        acc[mf][nf] = __builtin_amdgcn_mfma_f32_16x16x32_bf16(af[mf], bf[nf], acc[mf][nf], 0, 0, 0);
  }

#pragma unroll
  for (int mf = 0; mf < 4; ++mf) {
#pragma unroll
    for (int nf = 0; nf < 4; ++nf) {
#pragma unroll
      for (int r = 0; r < 4; ++r) {
        int row = m0 + wr * 64 + mf * 16 + lg * 4 + r;
        int col = n0 + wc * 64 + nf * 16 + lr;
        float v = acc[mf][nf][r];
        int b = row >> 10, tt = row & 1023;
        if (col < 1024) {
          v += b0[col];
          qb[(size_t)row * HD + col] = f2b(v * (SCALE * SCALE * LOG2E));
        } else if (col < 2048) {
          int hd = col - 1024;
          u16 kv16 = f2b(v + b1[hd]);
          kbp[(size_t)(b * 1024 + tt) * 1024 + hd] = kv16;
          int h = hd >> 6, d = hd & 63, jl = tt & 63, jc = 16 + (tt >> 6);
          kt[(((size_t)(b * 16 + h) * 32 + jc) * 4096) + jl * 64 + (d ^ ((jl & 7) << 3))] = kv16;
        } else {
          int hd = col - 2048;
          vb[(size_t)(b * 1024 + tt) * 1024 + hd] = f2b(v + b2[hd]);
        }
      }
    }
  }
}

// kvout [b][t][2][1024] f32 from plain bf16 k/v (coalesced)
__global__ __launch_bounds__(256) void kv_expand(const u16* __restrict__ kbp, const u16* __restrict__ vbp,
                                                 float* __restrict__ kvout) {
  int i = blockIdx.x * 256 + threadIdx.x;  // [0, 524288)
  int hd8 = i & 127, tt = (i >> 7) & 1023, b = i >> 17;
  size_t src = ((size_t)(b * 1024 + tt)) * 1024 + (size_t)hd8 * 8;
  short8 k8 = *(const short8*)&kbp[src];
  short8 v8 = *(const short8*)&vbp[src];
  float4 k0, k1, v0, v1;
#pragma unroll
  for (int e = 0; e < 4; ++e) {
    ((float*)&k0)[e] = b2f((u16)k8[e]); ((float*)&k1)[e] = b2f((u16)k8[e + 4]);
    ((float*)&v0)[e] = b2f((u16)v8[e]); ((float*)&v1)[e] = b2f((u16)v8[e + 4]);
  }
  float* kdst = kvout + (((size_t)(b * 1024 + tt) * 2 + 0) * 1024) + hd8 * 8;
  float* vdst = kvout + (((size_t)(b * 1024 + tt) * 2 + 1) * 1024) + hd8 * 8;
  ((float4*)kdst)[0] = k0; ((float4*)kdst)[1] = k1;
  ((float4*)vdst)[0] = v0; ((float4*)vdst)[1] = v1;
}

// ---------- out-proj GEMM: 64x128 tiles, 512 blocks ----------
__global__ __launch_bounds__(256) void gemm_out(
    const u16* __restrict__ A, const u16* __restrict__ BT,
    const float* __restrict__ bias, float* __restrict__ outf) {
  __shared__ __align__(16) u16 As[64 * 32];
  __shared__ __align__(16) u16 Bs[128 * 32];
  const int t = threadIdx.x;
  const int lane = t & 63, wv = t >> 6;
  const int wr = wv >> 1, wc = wv & 1;
  const int m0 = (blockIdx.x >> 3) * 64;
  const int n0 = (blockIdx.x & 7) * 128;
  const int lr = lane & 15, lg = lane >> 4;

  f32x4 acc[2][4] = {};

  for (int kc = 0; kc < 1024; kc += 32) {
    __syncthreads();
    gload_lds16(A + (size_t)(m0 + (t >> 2)) * 1024 + kc + (t & 3) * 8, &As[t * 8]);
#pragma unroll
    for (int i = 0; i < 2; ++i) {
      int p = t + 256 * i;
      gload_lds16(BT + (size_t)(n0 + (p >> 2)) * 1024 + kc + (p & 3) * 8, &Bs[p * 8]);
    }
    __syncthreads();

    short8 af[2], bf[4];
#pragma unroll
    for (int mf = 0; mf < 2; ++mf)
      af[mf] = *(const short8*)&As[(wr * 32 + mf * 16 + lr) * 32 + lg * 8];
#pragma unroll
    for (int nf = 0; nf < 4; ++nf)
      bf[nf] = *(const short8*)&Bs[(wc * 64 + nf * 16 + lr) * 32 + lg * 8];
#pragma unroll
    for (int mf = 0; mf < 2; ++mf)
#pragma unroll
      for (int nf = 0; nf < 4; ++nf)
        acc[mf][nf] = __builtin_amdgcn_mfma_f32_16x16x32_bf16(af[mf], bf[nf], acc[mf][nf], 0, 0, 0);
  }

#pragma unroll
  for (int mf = 0; mf < 2; ++mf)
#pragma unroll
    for (int nf = 0; nf < 4; ++nf)
#pragma unroll
      for (int r = 0; r < 4; ++r) {
        int row = m0 + wr * 32 + mf * 16 + lg * 4 + r;
        int col = n0 + wc * 64 + nf * 16 + lr;
        outf[(size_t)row * E_ + col] = acc[mf][nf][r] + bias[col];
      }
}

// ---------- flash attention: QBLK=64, octet-swizzled K/V, 2-deep rel prefetch ----------
__global__ __launch_bounds__(256, 4) void attn_kernel(
    const u16* __restrict__ qb, const u16* __restrict__ kt, const u16* __restrict__ vt,
    const float* __restrict__ rel, u16* __restrict__ aout) {
  __shared__ __align__(16) u16 Ks[2][4096];
  __shared__ __align__(16) u16 Vs[2][4096];
  __shared__ __align__(16) u16 Pl[4096];
  const int bx = blockIdx.x;
  const int b = bx & 3, h = (bx >> 2) & 15, qt = bx >> 6;  // qt high bits: balanced CUs
  const int i0 = qt * 64;
  const int t = threadIdx.x, lane = t & 63, w = t >> 6;
  const int lr = lane & 15, lg = lane >> 4;
  const int swz = (lr & 7) << 3;         // octet swizzle: conflict-free K/V b128 reads
  const int psw = ((lr >> 2) & 3) << 4;  // P-tile swizzle
  const float RC = SCALE * LOG2E;

  const u16* ktb = kt + (size_t)(b * 16 + h) * 32 * 4096;
  const u16* vtb = vt + (size_t)(b * 16 + h) * 32 * 4096;
  const float* relbase = rel + (size_t)h * T_ * JTOT;
  const int ib = i0 + w * 16 + lg * 4;

  short8 qf[2];
#pragma unroll
  for (int kc = 0; kc < 2; ++kc)
    qf[kc] = *(const short8*)&qb[(size_t)(b * T_ + i0 + w * 16 + lr) * HD + h * 64 + kc * 32 + lg * 8];

  short8 vf5;
#pragma unroll
  for (int e = 0; e < 8; ++e) vf5[e] = (lr == 0) ? (short)0x3f80 : (short)0;

  const int nch = qt + 17;

  auto stage = [&](int buf, int jc2) {  // 4 VMEM instrs/thread
    const u16* ksrc = ktb + (size_t)jc2 * 4096;
    const u16* vsrc = vtb + (size_t)jc2 * 4096;
    gload_lds16(ksrc + t * 8, &Ks[buf][t * 8]);
    gload_lds16(ksrc + (t + 256) * 8, &Ks[buf][(t + 256) * 8]);
    gload_lds16(vsrc + t * 8, &Vs[buf][t * 8]);
    gload_lds16(vsrc + (t + 256) * 8, &Vs[buf][(t + 256) * 8]);
  };

  auto loadrel = [&](int j0, float (&rlf)[4][4]) {  // 16 VMEM dword loads/thread
#pragma unroll
    for (int nf = 0; nf < 4; ++nf)
#pragma unroll
      for (int r = 0; r < 4; ++r)
        rlf[nf][r] = relbase[(size_t)(ib + r) * JTOT + j0 + nf * 16 + lr];
  };

  float rlA[4][4], rlB[4][4];
  stage(0, 0);
  __builtin_amdgcn_sched_barrier(0);  // stage(0) VMEM issued first: vmcnt counting valid
  loadrel(0, rlA);
  loadrel(64, rlB);

  f32x4 o[5] = {};  // o[4] = running row-sum via ones-column MFMA
  float mrow[4];
#pragma unroll
  for (int r = 0; r < 4; ++r) mrow[r] = -__builtin_inff();

  int cur = 0;
  auto chunkfn = [&](int jc, float (&rlu)[4][4]) {
    // outstanding (oldest->newest): rel(jc) 16, stage(jc) 4, rel(jc+1) 16.
    // vmcnt(16): drains rel(jc) + stage(jc); rel(jc+1) stays in flight across barrier.
    asm volatile("s_waitcnt vmcnt(16)" ::: "memory");
    __builtin_amdgcn_sched_barrier(0);
    asm volatile("s_barrier" ::: "memory");
    if (jc + 1 < nch) stage(cur ^ 1, jc + 1);
    __builtin_amdgcn_sched_barrier(0);

    // S = Q K^T (log2 domain)
    f32x4 s4[4] = {};
    __builtin_amdgcn_s_setprio(1);
#pragma unroll
    for (int nf = 0; nf < 4; ++nf)
#pragma unroll
      for (int kc = 0; kc < 2; ++kc) {
        short8 kf = *(const short8*)&Ks[cur][(nf * 16 + lr) * 64 + ((kc * 32 + lg * 8) ^ swz)];
        s4[nf] = __builtin_amdgcn_mfma_f32_16x16x32_bf16(qf[kc], kf, s4[nf], 0, 0, 0);
      }
    __builtin_amdgcn_s_setprio(0);

    // logits + in-lane max
    float p[4][4], lmax[4];
    const bool domask = (jc == qt + 16);
#pragma unroll
    for (int nf = 0; nf < 4; ++nf)
#pragma unroll
      for (int r = 0; r < 4; ++r) {
        float v = fmaf(rlu[nf][r], RC, s4[nf][r]);
        if (domask && (nf * 16 + lr) > (w * 16 + lg * 4 + r)) v = -__builtin_inff();
        p[nf][r] = v;
      }
    // refill same buffer with rel(jc+2): 2-chunk latency coverage
    if (jc + 2 < nch) loadrel((jc + 2) * 64, rlu);
#pragma unroll
    for (int r = 0; r < 4; ++r)
      lmax[r] = fmaxf(fmaxf(p[0][r], p[1][r]), fmaxf(p[2][r], p[3][r]));

    // defer-max: cross-lane tree only when rescale needed
    float need = -__builtin_inff();
#pragma unroll
    for (int r = 0; r < 4; ++r) need = fmaxf(need, lmax[r] - mrow[r]);
    const bool dores = !__all(need <= 11.0f);
    if (dores) {
      float chmax[4], sc[4];
#pragma unroll
      for (int r = 0; r < 4; ++r) chmax[r] = lmax[r];
#pragma unroll
      for (int msk = 1; msk <= 8; msk <<= 1)
#pragma unroll
        for (int r = 0; r < 4; ++r)
          chmax[r] = fmaxf(chmax[r], __shfl_xor(chmax[r], msk, 64));
#pragma unroll
      for (int r = 0; r < 4; ++r) {
        float nm = fmaxf(mrow[r], chmax[r]);
        sc[r] = fexp2(mrow[r] - nm);
        mrow[r] = nm;
      }
#pragma unroll
      for (int nf = 0; nf < 5; ++nf)
#pragma unroll
        for (int r = 0; r < 4; ++r) o[nf][r] *= sc[r];
    }

    // P = exp2(p - m) -> wave-private swizzled LDS
#pragma unroll
    for (int nf = 0; nf < 4; ++nf)
#pragma unroll
      for (int r = 0; r < 4; ++r) {
        float pe = fexp2(p[nf][r] - mrow[r]);
        Pl[(w * 16 + lg * 4 + r) * 64 + (((nf ^ lg) << 4) + lr)] = f2b_fast(pe);
      }

    // O += P @ V; ones-block MFMA accumulates row-sum into o[4]
    __builtin_amdgcn_s_setprio(1);
#pragma unroll
    for (int kc = 0; kc < 2; ++kc) {
      const int pcol = kc * 32 + lg * 8;
      short8 pa = *(const short8*)&Pl[(w * 16 + lr) * 64 + (pcol ^ psw)];
#pragma unroll
      for (int nf = 0; nf < 4; ++nf) {
        short8 vf = *(const short8*)&Vs[cur][(nf * 16 + lr) * 64 + (pcol ^ swz)];
        o[nf] = __builtin_amdgcn_mfma_f32_16x16x32_bf16(pa, vf, o[nf], 0, 0, 0);
      }
      o[4] = __builtin_amdgcn_mfma_f32_16x16x32_bf16(pa, vf5, o[4], 0, 0, 0);
    }
    __builtin_amdgcn_s_setprio(0);
    cur ^= 1;
  };

  int jc = 0;
  for (; jc + 1 < nch; jc += 2) {  // static unroll-2: rlA/rlB never runtime-indexed
    chunkfn(jc, rlA);
    chunkfn(jc + 1, rlB);
  }
  if (jc < nch) chunkfn(jc, rlA);

  float inv[4];
#pragma unroll
  for (int r = 0; r < 4; ++r)
    inv[r] = 1.0f / __shfl(o[4][r], lane & 48, 64);
#pragma unroll
  for (int nf = 0; nf < 4; ++nf)
#pragma unroll
    for (int r = 0; r < 4; ++r) {
      int i = i0 + w * 16 + lg * 4 + r, d = nf * 16 + lr;
      aout[(size_t)(b * T_ + i) * HD + h * 64 + d] = f2b_fast(o[nf][r] * inv[r]);
    }
}

// ---------- launch ----------
extern "C" void kernel_launch(void* const* d_in, const int* in_sizes, int n_in,
                              void* d_out, int out_size, void* d_ws, size_t ws_size,
                              hipStream_t stream) {
  const float* x  = (const float*)d_in[0];
  const float* xl = (const float*)d_in[1];
  const float* rel = (const float*)d_in[2];
  const float* Wq = (const float*)d_in[3];
  const float* bq = (const float*)d_in[4];
  const float* Wk = (const float*)d_in[5];
  const float* bk = (const float*)d_in[6];
  const float* Wv = (const float*)d_in[7];
  const float* bv = (const float*)d_in[8];
  const float* Wo = (const float*)d_in[9];
  const float* bo = (const float*)d_in[10];

  float* out = (float*)d_out;
  float* kvout = out + (size_t)B_ * T_ * E_;

  char* ws = (char*)d_ws;
  u16* xb    = (u16*)ws; ws += (size_t)4096 * 1024 * 2;
  u16* wqkvT = (u16*)ws; ws += (size_t)3072 * 1024 * 2;
  u16* woT   = (u16*)ws; ws += (size_t)1024 * 1024 * 2;
  u16* qbuf  = (u16*)ws; ws += (size_t)4096 * 1024 * 2;
  u16* kt    = (u16*)ws; ws += (size_t)B_ * NH * 32 * 4096 * 2;
  u16* vt    = (u16*)ws; ws += (size_t)B_ * NH * 32 * 4096 * 2;
  u16* vbn   = (u16*)ws; ws += (size_t)4096 * 1024 * 2;
  u16* kbp   = (u16*)ws; ws += (size_t)4096 * 1024 * 2;
  u16* aout  = (u16*)ws; ws += (size_t)4096 * 1024 * 2;

  cvt_bf16<<<2048, 256, 0, stream>>>(x, xb, 524288);
  cvt_w4T<<<dim3(16, 16, 4), 256, 0, stream>>>(Wq, Wk, Wv, Wo, wqkvT, woT);
  cvt_xl_k<<<2048, 256, 0, stream>>>(xl, kt);
  cvt_xl_vT<<<1024, 256, 0, stream>>>(xl, vt);

  gemm_qkv<<<32 * 24, 256, 0, stream>>>(xb, wqkvT, bq, bk, bv, qbuf, kbp, kt, vbn);
  kv_expand<<<2048, 256, 0, stream>>>(kbp, vbn, kvout);
  trans_vnew<<<1024, 256, 0, stream>>>(vbn, vt);
  attn_kernel<<<1024, 256, 0, stream>>>(qbuf, kt, vt, rel, aout);
  gemm_out<<<512, 256, 0, stream>>>(aout, woT, bo, out);
}

// Round 8
// 211.373 us; speedup vs baseline: 1.2111x; 1.0710x over previous
//
#include <hip/hip_runtime.h>
#include <hip/hip_bf16.h>

typedef unsigned short u16;
typedef unsigned int u32;
typedef __attribute__((ext_vector_type(8))) short short8;
typedef __attribute__((ext_vector_type(4))) float f32x4;

#define B_ 4
#define T_ 1024
#define E_ 1024
#define NH 16
#define HD 1024
#define JTOT 2048
#define SCALE 0.125f
#define LOG2E 1.44269504f

// ---------- helpers ----------
__device__ __forceinline__ u16 f2b(float f) {
  u32 x = __float_as_uint(f);
  u32 r = (x + 0x7fffu + ((x >> 16) & 1u)) >> 16;  // RNE
  return (u16)r;
}
__device__ __forceinline__ u16 f2b_fast(float f) {  // round-half-up (2 ops)
  return (u16)((__float_as_uint(f) + 0x8000u) >> 16);
}
__device__ __forceinline__ float b2f(u16 b) {
  return __uint_as_float((u32)b << 16);
}
__device__ __forceinline__ float fexp2(float x) {
  float r;
  asm("v_exp_f32 %0, %1" : "=v"(r) : "v"(x));
  return r;
}

__device__ __forceinline__ void gload_lds16(const void* g, void* l) {
  __builtin_amdgcn_global_load_lds((const __attribute__((address_space(1))) u32*)g,
                                   (__attribute__((address_space(3))) u32*)l, 16, 0, 0);
}

__device__ __forceinline__ short8 pack8(float4 f0, float4 f1) {
  short8 o;
  o[0] = (short)f2b(f0.x); o[1] = (short)f2b(f0.y);
  o[2] = (short)f2b(f0.z); o[3] = (short)f2b(f0.w);
  o[4] = (short)f2b(f1.x); o[5] = (short)f2b(f1.y);
  o[6] = (short)f2b(f1.z); o[7] = (short)f2b(f1.w);
  return o;
}

// ---------- conversion kernels ----------
__global__ __launch_bounds__(256) void cvt_bf16(const float* __restrict__ in,
                                                u16* __restrict__ out, int n8) {
  int i = blockIdx.x * 256 + threadIdx.x;
  if (i >= n8) return;
  const float4* p = (const float4*)in + (size_t)i * 2;
  ((short8*)out)[i] = pack8(p[0], p[1]);
}

// fused 4x: W [1024][1024] f32 -> WT bf16 transposed
__global__ __launch_bounds__(256) void cvt_w4T(const float* __restrict__ Wq, const float* __restrict__ Wk,
                                               const float* __restrict__ Wv, const float* __restrict__ Wo,
                                               u16* __restrict__ wqkvT, u16* __restrict__ woT) {
  __shared__ float tile[64][65];
  const float* W;
  u16* WT;
  int z = blockIdx.z;
  if (z == 0) { W = Wq; WT = wqkvT; }
  else if (z == 1) { W = Wk; WT = wqkvT + (size_t)1024 * 1024; }
  else if (z == 2) { W = Wv; WT = wqkvT + (size_t)2048 * 1024; }
  else { W = Wo; WT = woT; }
  int t = threadIdx.x;
  int r0 = blockIdx.y * 64, c0 = blockIdx.x * 64;
#pragma unroll
  for (int i = 0; i < 16; ++i) {
    int r = i * 4 + (t >> 6), c = t & 63;
    tile[r][c] = W[(size_t)(r0 + r) * 1024 + c0 + c];
  }
  __syncthreads();
#pragma unroll
  for (int i = 0; i < 16; ++i) {
    int r = i * 4 + (t >> 6), c = t & 63;
    WT[(size_t)(c0 + r) * 1024 + r0 + c] = f2b(tile[c][r]);
  }
}

// xl k-half -> kt tiles [B][H][jc 0..15][64 j][64 d ^ octet-swz] bf16
__global__ __launch_bounds__(256) void cvt_xl_k(const float* __restrict__ xl, u16* __restrict__ kt) {
  int i = blockIdx.x * 256 + threadIdx.x;  // [0, 524288)
  int hd8 = i & 127, j = (i >> 7) & 1023, b = i >> 17;
  const float4* p = (const float4*)(xl + ((((size_t)b * 1024 + j) * 2 + 0) * 1024 + (size_t)hd8 * 8));
  short8 o = pack8(p[0], p[1]);
  int h = hd8 >> 3, d0 = (hd8 & 7) * 8;
  int jc = j >> 6, jl = j & 63;
  u16* dst = kt + (((size_t)(b * 16 + h) * 32 + jc) * 4096) + jl * 64 + (d0 ^ ((jl & 7) << 3));
  *(short8*)dst = o;
}

// xl v-half -> vt tiles [B][H][jc 0..15][64 d][64 j ^ octet-swz] bf16 (transposed)
__global__ __launch_bounds__(256) void cvt_xl_vT(const float* __restrict__ xl, u16* __restrict__ vt) {
  __shared__ u16 Vl[64 * 72];
  int bx = blockIdx.x;
  int jc = bx & 15, h = (bx >> 4) & 15, b = bx >> 8;
  int t = threadIdx.x;
  int j0 = jc * 64;
#pragma unroll
  for (int it = 0; it < 2; ++it) {
    int p = t + 256 * it;
    int j = p >> 3, d8 = p & 7;
    const float4* src = (const float4*)(xl + ((((size_t)b * 1024 + j0 + j) * 2 + 1) * 1024 + h * 64 + (size_t)d8 * 8));
    *(short8*)&Vl[j * 72 + d8 * 8] = pack8(src[0], src[1]);
  }
  __syncthreads();
#pragma unroll
  for (int it = 0; it < 2; ++it) {
    int p = t + 256 * it;
    int d = p >> 3, j8 = p & 7;
    short8 o;
#pragma unroll
    for (int e = 0; e < 8; ++e) o[e] = (short)Vl[(j8 * 8 + e) * 72 + d];
    u16* dst = vt + (((size_t)(b * 16 + h) * 32 + jc) * 4096) + d * 64 + ((j8 * 8) ^ ((d & 7) << 3));
    *(short8*)dst = o;
  }
}

// vb_new [b][tt][hd] bf16 -> vt tiles jc 16..31 (transposed + octet-swizzled)
__global__ __launch_bounds__(256) void trans_vnew(const u16* __restrict__ vb, u16* __restrict__ vt) {
  __shared__ u16 Vl[64 * 72];
  int bx = blockIdx.x;
  int jcl = bx & 15, h = (bx >> 4) & 15, b = bx >> 8;
  int jc = 16 + jcl;
  int t = threadIdx.x;
  int t0 = jcl * 64;
#pragma unroll
  for (int it = 0; it < 2; ++it) {
    int p = t + 256 * it;
    int j = p >> 3, d8 = p & 7;
    *(short8*)&Vl[j * 72 + d8 * 8] =
        *(const short8*)&vb[((size_t)b * 1024 + t0 + j) * 1024 + h * 64 + d8 * 8];
  }
  __syncthreads();
#pragma unroll
  for (int it = 0; it < 2; ++it) {
    int p = t + 256 * it;
    int d = p >> 3, j8 = p & 7;
    short8 o;
#pragma unroll
    for (int e = 0; e < 8; ++e) o[e] = (short)Vl[(j8 * 8 + e) * 72 + d];
    u16* dst = vt + (((size_t)(b * 16 + h) * 32 + jc) * 4096) + d * 64 + ((j8 * 8) ^ ((d & 7) << 3));
    *(short8*)dst = o;
  }
}

// ---------- QKV GEMM: 128x128 tiles, slim epilogue ----------
__global__ __launch_bounds__(256) void gemm_qkv(
    const u16* __restrict__ A, const u16* __restrict__ BT,
    const float* __restrict__ b0, const float* __restrict__ b1, const float* __restrict__ b2,
    u16* __restrict__ qb, u16* __restrict__ kbp, u16* __restrict__ kt, u16* __restrict__ vb) {
  __shared__ __align__(16) u16 As[128 * 32];
  __shared__ __align__(16) u16 Bs[128 * 32];
  const int t = threadIdx.x;
  const int lane = t & 63, wv = t >> 6;
  const int wr = wv >> 1, wc = wv & 1;
  const int m0 = (blockIdx.x / 24) * 128;
  const int n0 = (blockIdx.x % 24) * 128;
  const int lr = lane & 15, lg = lane >> 4;

  f32x4 acc[4][4] = {};

  for (int kc = 0; kc < 1024; kc += 32) {
    __syncthreads();
#pragma unroll
    for (int i = 0; i < 2; ++i) {
      int p = t + 256 * i;
      gload_lds16(A + (size_t)(m0 + (p >> 2)) * 1024 + kc + (p & 3) * 8, &As[p * 8]);
    }
#pragma unroll
    for (int i = 0; i < 2; ++i) {
      int p = t + 256 * i;
      gload_lds16(BT + (size_t)(n0 + (p >> 2)) * 1024 + kc + (p & 3) * 8, &Bs[p * 8]);
    }
    __syncthreads();

    short8 af[4], bf[4];
#pragma unroll
    for (int mf = 0; mf < 4; ++mf)
      af[mf] = *(const short8*)&As[(wr * 64 + mf * 16 + lr) * 32 + lg * 8];
#pragma unroll
    for (int nf = 0; nf < 4; ++nf)
      bf[nf] = *(const short8*)&Bs[(wc * 64 + nf * 16 + lr) * 32 + lg * 8];
#pragma unroll
    for (int mf = 0; mf < 4; ++mf)
#pragma unroll
      for (int nf = 0; nf < 4; ++nf)
        acc[mf][nf] = __builtin_amdgcn_mfma_f32_16x16x32_bf16(af[mf], bf[nf], acc[mf][nf], 0, 0, 0);
  }

#pragma unroll
  for (int mf = 0; mf < 4; ++mf) {
#pragma unroll
    for (int nf = 0; nf < 4; ++nf) {
#pragma unroll
      for (int r = 0; r < 4; ++r) {
        int row = m0 + wr * 64 + mf * 16 + lg * 4 + r;
        int col = n0 + wc * 64 + nf * 16 + lr;
        float v = acc[mf][nf][r];
        int b = row >> 10, tt = row & 1023;
        if (col < 1024) {
          v += b0[col];
          qb[(size_t)row * HD + col] = f2b(v * (SCALE * SCALE * LOG2E));
        } else if (col < 2048) {
          int hd = col - 1024;
          u16 kv16 = f2b(v + b1[hd]);
          kbp[(size_t)(b * 1024 + tt) * 1024 + hd] = kv16;
          int h = hd >> 6, d = hd & 63, jl = tt & 63, jc = 16 + (tt >> 6);
          kt[(((size_t)(b * 16 + h) * 32 + jc) * 4096) + jl * 64 + (d ^ ((jl & 7) << 3))] = kv16;
        } else {
          int hd = col - 2048;
          vb[(size_t)(b * 1024 + tt) * 1024 + hd] = f2b(v + b2[hd]);
        }
      }
    }
  }
}

// kvout [b][t][2][1024] f32 from plain bf16 k/v (coalesced)
__global__ __launch_bounds__(256) void kv_expand(const u16* __restrict__ kbp, const u16* __restrict__ vbp,
                                                 float* __restrict__ kvout) {
  int i = blockIdx.x * 256 + threadIdx.x;  // [0, 524288)
  int hd8 = i & 127, tt = (i >> 7) & 1023, b = i >> 17;
  size_t src = ((size_t)(b * 1024 + tt)) * 1024 + (size_t)hd8 * 8;
  short8 k8 = *(const short8*)&kbp[src];
  short8 v8 = *(const short8*)&vbp[src];
  float4 k0, k1, v0, v1;
#pragma unroll
  for (int e = 0; e < 4; ++e) {
    ((float*)&k0)[e] = b2f((u16)k8[e]); ((float*)&k1)[e] = b2f((u16)k8[e + 4]);
    ((float*)&v0)[e] = b2f((u16)v8[e]); ((float*)&v1)[e] = b2f((u16)v8[e + 4]);
  }
  float* kdst = kvout + (((size_t)(b * 1024 + tt) * 2 + 0) * 1024) + hd8 * 8;
  float* vdst = kvout + (((size_t)(b * 1024 + tt) * 2 + 1) * 1024) + hd8 * 8;
  ((float4*)kdst)[0] = k0; ((float4*)kdst)[1] = k1;
  ((float4*)vdst)[0] = v0; ((float4*)vdst)[1] = v1;
}

// ---------- out-proj GEMM: 64x128 tiles, 512 blocks ----------
__global__ __launch_bounds__(256) void gemm_out(
    const u16* __restrict__ A, const u16* __restrict__ BT,
    const float* __restrict__ bias, float* __restrict__ outf) {
  __shared__ __align__(16) u16 As[64 * 32];
  __shared__ __align__(16) u16 Bs[128 * 32];
  const int t = threadIdx.x;
  const int lane = t & 63, wv = t >> 6;
  const int wr = wv >> 1, wc = wv & 1;
  const int m0 = (blockIdx.x >> 3) * 64;
  const int n0 = (blockIdx.x & 7) * 128;
  const int lr = lane & 15, lg = lane >> 4;

  f32x4 acc[2][4] = {};

  for (int kc = 0; kc < 1024; kc += 32) {
    __syncthreads();
    gload_lds16(A + (size_t)(m0 + (t >> 2)) * 1024 + kc + (t & 3) * 8, &As[t * 8]);
#pragma unroll
    for (int i = 0; i < 2; ++i) {
      int p = t + 256 * i;
      gload_lds16(BT + (size_t)(n0 + (p >> 2)) * 1024 + kc + (p & 3) * 8, &Bs[p * 8]);
    }
    __syncthreads();

    short8 af[2], bf[4];
#pragma unroll
    for (int mf = 0; mf < 2; ++mf)
      af[mf] = *(const short8*)&As[(wr * 32 + mf * 16 + lr) * 32 + lg * 8];
#pragma unroll
    for (int nf = 0; nf < 4; ++nf)
      bf[nf] = *(const short8*)&Bs[(wc * 64 + nf * 16 + lr) * 32 + lg * 8];
#pragma unroll
    for (int mf = 0; mf < 2; ++mf)
#pragma unroll
      for (int nf = 0; nf < 4; ++nf)
        acc[mf][nf] = __builtin_amdgcn_mfma_f32_16x16x32_bf16(af[mf], bf[nf], acc[mf][nf], 0, 0, 0);
  }

#pragma unroll
  for (int mf = 0; mf < 2; ++mf)
#pragma unroll
    for (int nf = 0; nf < 4; ++nf)
#pragma unroll
      for (int r = 0; r < 4; ++r) {
        int row = m0 + wr * 32 + mf * 16 + lg * 4 + r;
        int col = n0 + wc * 64 + nf * 16 + lr;
        outf[(size_t)row * E_ + col] = acc[mf][nf][r] + bias[col];
      }
}

// ---------- flash attention: XCD-pinned rel reuse + 2-deep rel prefetch (no spill) ----------
__global__ __launch_bounds__(256) void attn_kernel(
    const u16* __restrict__ qb, const u16* __restrict__ kt, const u16* __restrict__ vt,
    const float* __restrict__ rel, u16* __restrict__ aout) {
  __shared__ __align__(16) u16 Ks[2][4096];
  __shared__ __align__(16) u16 Vs[2][4096];
  __shared__ __align__(16) u16 Pl[4096];
  const int bx = blockIdx.x;
  // XCD pinning: all 4 b-variants of one (h,qt) share an XCD -> rel slice L2-resident.
  // xcd = key&7 (blockIdx round-robins across 8 XCDs); per-CU qt mix {q,q+4,q+8,q+12}.
  const int xcd = bx & 7, s = bx >> 3;
  const int b = s & 3, key = (s >> 2) * 8 + xcd;
  const int h = key & 15, qt = key >> 4;
  const int i0 = qt * 64;
  const int t = threadIdx.x, lane = t & 63, w = t >> 6;
  const int lr = lane & 15, lg = lane >> 4;
  const int swz = (lr & 7) << 3;         // octet swizzle: conflict-free K/V b128 reads
  const int psw = ((lr >> 2) & 3) << 4;  // P-tile swizzle
  const float RC = SCALE * LOG2E;

  const u16* ktb = kt + (size_t)(b * 16 + h) * 32 * 4096;
  const u16* vtb = vt + (size_t)(b * 16 + h) * 32 * 4096;
  const float* relbase = rel + (size_t)h * T_ * JTOT;
  const int ib = i0 + w * 16 + lg * 4;

  short8 qf[2];
#pragma unroll
  for (int kc = 0; kc < 2; ++kc)
    qf[kc] = *(const short8*)&qb[(size_t)(b * T_ + i0 + w * 16 + lr) * HD + h * 64 + kc * 32 + lg * 8];

  short8 vf5;
#pragma unroll
  for (int e = 0; e < 8; ++e) vf5[e] = (lr == 0) ? (short)0x3f80 : (short)0;

  const int nch = qt + 17;

  auto stage = [&](int buf, int jc2) {  // 4 VMEM instrs/thread
    const u16* ksrc = ktb + (size_t)jc2 * 4096;
    const u16* vsrc = vtb + (size_t)jc2 * 4096;
    gload_lds16(ksrc + t * 8, &Ks[buf][t * 8]);
    gload_lds16(ksrc + (t + 256) * 8, &Ks[buf][(t + 256) * 8]);
    gload_lds16(vsrc + t * 8, &Vs[buf][t * 8]);
    gload_lds16(vsrc + (t + 256) * 8, &Vs[buf][(t + 256) * 8]);
  };

  auto loadrel = [&](int j0, float (&rlf)[4][4]) {  // 16 VMEM dword loads/thread
#pragma unroll
    for (int nf = 0; nf < 4; ++nf)
#pragma unroll
      for (int r = 0; r < 4; ++r)
        rlf[nf][r] = relbase[(size_t)(ib + r) * JTOT + j0 + nf * 16 + lr];
  };

  float rlA[4][4], rlB[4][4];
  stage(0, 0);
  __builtin_amdgcn_sched_barrier(0);  // stage(0) VMEM issued first: vmcnt counting valid
  loadrel(0, rlA);
  loadrel(64, rlB);

  f32x4 o[5] = {};  // o[4] = running row-sum via ones-column MFMA
  float mrow[4];
#pragma unroll
  for (int r = 0; r < 4; ++r) mrow[r] = -__builtin_inff();

  int cur = 0;
  auto chunkfn = [&](int jc, float (&rlu)[4][4]) {
    // outstanding (oldest->newest): rel(jc) 16, stage(jc) 4, rel(jc+1) 16.
    // vmcnt(16): drains rel(jc)+stage(jc); rel(jc+1) stays in flight across barrier.
    asm volatile("s_waitcnt vmcnt(16)" ::: "memory");
    __builtin_amdgcn_sched_barrier(0);
    asm volatile("s_barrier" ::: "memory");
    if (jc + 1 < nch) stage(cur ^ 1, jc + 1);
    __builtin_amdgcn_sched_barrier(0);

    // S = Q K^T (log2 domain)
    f32x4 s4[4] = {};
    __builtin_amdgcn_s_setprio(1);
#pragma unroll
    for (int nf = 0; nf < 4; ++nf)
#pragma unroll
      for (int kc = 0; kc < 2; ++kc) {
        short8 kf = *(const short8*)&Ks[cur][(nf * 16 + lr) * 64 + ((kc * 32 + lg * 8) ^ swz)];
        s4[nf] = __builtin_amdgcn_mfma_f32_16x16x32_bf16(qf[kc], kf, s4[nf], 0, 0, 0);
      }
    __builtin_amdgcn_s_setprio(0);

    // logits + in-lane max
    float p[4][4], lmax[4];
    const bool domask = (jc == qt + 16);
#pragma unroll
    for (int nf = 0; nf < 4; ++nf)
#pragma unroll
      for (int r = 0; r < 4; ++r) {
        float v = fmaf(rlu[nf][r], RC, s4[nf][r]);
        if (domask && (nf * 16 + lr) > (w * 16 + lg * 4 + r)) v = -__builtin_inff();
        p[nf][r] = v;
      }
    // refill same buffer with rel(jc+2): 2-chunk latency coverage
    if (jc + 2 < nch) loadrel((jc + 2) * 64, rlu);
#pragma unroll
    for (int r = 0; r < 4; ++r)
      lmax[r] = fmaxf(fmaxf(p[0][r], p[1][r]), fmaxf(p[2][r], p[3][r]));

    // defer-max: cross-lane tree only when rescale needed
    float need = -__builtin_inff();
#pragma unroll
    for (int r = 0; r < 4; ++r) need = fmaxf(need, lmax[r] - mrow[r]);
    const bool dores = !__all(need <= 11.0f);
    if (dores) {
      float chmax[4], sc[4];
#pragma unroll
      for (int r = 0; r < 4; ++r) chmax[r] = lmax[r];
#pragma unroll
      for (int msk = 1; msk <= 8; msk <<= 1)
#pragma unroll
        for (int r = 0; r < 4; ++r)
          chmax[r] = fmaxf(chmax[r], __shfl_xor(chmax[r], msk, 64));
#pragma unroll
      for (int r = 0; r < 4; ++r) {
        float nm = fmaxf(mrow[r], chmax[r]);
        sc[r] = fexp2(mrow[r] - nm);
        mrow[r] = nm;
      }
#pragma unroll
      for (int nf = 0; nf < 5; ++nf)
#pragma unroll
        for (int r = 0; r < 4; ++r) o[nf][r] *= sc[r];
    }

    // P = exp2(p - m) -> wave-private swizzled LDS
#pragma unroll
    for (int nf = 0; nf < 4; ++nf)
#pragma unroll
      for (int r = 0; r < 4; ++r) {
        float pe = fexp2(p[nf][r] - mrow[r]);
        Pl[(w * 16 + lg * 4 + r) * 64 + (((nf ^ lg) << 4) + lr)] = f2b_fast(pe);
      }

    // O += P @ V; ones-block MFMA accumulates row-sum into o[4]
    __builtin_amdgcn_s_setprio(1);
#pragma unroll
    for (int kc = 0; kc < 2; ++kc) {
      const int pcol = kc * 32 + lg * 8;
      short8 pa = *(const short8*)&Pl[(w * 16 + lr) * 64 + (pcol ^ psw)];
#pragma unroll
      for (int nf = 0; nf < 4; ++nf) {
        short8 vf = *(const short8*)&Vs[cur][(nf * 16 + lr) * 64 + (pcol ^ swz)];
        o[nf] = __builtin_amdgcn_mfma_f32_16x16x32_bf16(pa, vf, o[nf], 0, 0, 0);
      }
      o[4] = __builtin_amdgcn_mfma_f32_16x16x32_bf16(pa, vf5, o[4], 0, 0, 0);
    }
    __builtin_amdgcn_s_setprio(0);
    cur ^= 1;
  };

  int jc = 0;
  for (; jc + 1 < nch; jc += 2) {  // static unroll-2: rlA/rlB never runtime-indexed
    chunkfn(jc, rlA);
    chunkfn(jc + 1, rlB);
  }
  if (jc < nch) chunkfn(jc, rlA);

  float inv[4];
#pragma unroll
  for (int r = 0; r < 4; ++r)
    inv[r] = 1.0f / __shfl(o[4][r], lane & 48, 64);
#pragma unroll
  for (int nf = 0; nf < 4; ++nf)
#pragma unroll
    for (int r = 0; r < 4; ++r) {
      int i = i0 + w * 16 + lg * 4 + r, d = nf * 16 + lr;
      aout[(size_t)(b * T_ + i) * HD + h * 64 + d] = f2b_fast(o[nf][r] * inv[r]);
    }
}

// ---------- launch ----------
extern "C" void kernel_launch(void* const* d_in, const int* in_sizes, int n_in,
                              void* d_out, int out_size, void* d_ws, size_t ws_size,
                              hipStream_t stream) {
  const float* x  = (const float*)d_in[0];
  const float* xl = (const float*)d_in[1];
  const float* rel = (const float*)d_in[2];
  const float* Wq = (const float*)d_in[3];
  const float* bq = (const float*)d_in[4];
  const float* Wk = (const float*)d_in[5];
  const float* bk = (const float*)d_in[6];
  const float* Wv = (const float*)d_in[7];
  const float* bv = (const float*)d_in[8];
  const float* Wo = (const float*)d_in[9];
  const float* bo = (const float*)d_in[10];

  float* out = (float*)d_out;
  float* kvout = out + (size_t)B_ * T_ * E_;

  char* ws = (char*)d_ws;
  u16* xb    = (u16*)ws; ws += (size_t)4096 * 1024 * 2;
  u16* wqkvT = (u16*)ws; ws += (size_t)3072 * 1024 * 2;
  u16* woT   = (u16*)ws; ws += (size_t)1024 * 1024 * 2;
  u16* qbuf  = (u16*)ws; ws += (size_t)4096 * 1024 * 2;
  u16* kt    = (u16*)ws; ws += (size_t)B_ * NH * 32 * 4096 * 2;
  u16* vt    = (u16*)ws; ws += (size_t)B_ * NH * 32 * 4096 * 2;
  u16* vbn   = (u16*)ws; ws += (size_t)4096 * 1024 * 2;
  u16* kbp   = (u16*)ws; ws += (size_t)4096 * 1024 * 2;
  u16* aout  = (u16*)ws; ws += (size_t)4096 * 1024 * 2;

  cvt_bf16<<<2048, 256, 0, stream>>>(x, xb, 524288);
  cvt_w4T<<<dim3(16, 16, 4), 256, 0, stream>>>(Wq, Wk, Wv, Wo, wqkvT, woT);
  cvt_xl_k<<<2048, 256, 0, stream>>>(xl, kt);
  cvt_xl_vT<<<1024, 256, 0, stream>>>(xl, vt);

  gemm_qkv<<<32 * 24, 256, 0, stream>>>(xb, wqkvT, bq, bk, bv, qbuf, kbp, kt, vbn);
  kv_expand<<<2048, 256, 0, stream>>>(kbp, vbn, kvout);
  trans_vnew<<<1024, 256, 0, stream>>>(vbn, vt);
  attn_kernel<<<1024, 256, 0, stream>>>(qbuf, kt, vt, rel, aout);
  gemm_out<<<512, 256, 0, stream>>>(aout, woT, bo, out);
}